// Round 7
// baseline (156.381 us; speedup 1.0000x reference)
//
#include <hip/hip_runtime.h>

#define B_SZ   8
#define SEQ    2048
#define PSEQ   (SEQ+16)     // 16 zero pad rows before each batch
#define SDIM   1024
#define DIN    512
#define DOUT   512
#define KX     10
#define RTOT   (B_SZ*SEQ)   // 16384
#define LC     64
#define NC     (SEQ/LC)     // 32

typedef __attribute__((ext_vector_type(8))) short short8;
typedef __attribute__((ext_vector_type(4))) float f32x4;
typedef __attribute__((ext_vector_type(4))) unsigned short bfx4;

// ---- workspace layout (bytes) ----
#define OFF_XP   0UL             // B_SZ*PSEQ*DIN*2      = 16,908,288
#define OFF_UB   16908288UL      // RTOT*SDIM*2 (bf16)   = 33,554,432
#define OFF_HS   50462720UL      // RTOT*SDIM*2 (bf16)   = 33,554,432
#define OFF_BT   84017152UL      // SDIM*DIN*2           = 1,048,576
#define OFF_CT   85065728UL      // DOUT*SDIM*2          = 1,048,576
#define OFF_MT   86114304UL      // KX*DOUT*DIN*2        = 5,242,880

__device__ __forceinline__ short f2bf(float f) {
  unsigned u = __builtin_bit_cast(unsigned, f);
  u += 0x7fffu + ((u >> 16) & 1u);   // RNE
  return (short)(u >> 16);
}
__device__ __forceinline__ float bf2f(unsigned short b) {
  return __builtin_bit_cast(float, (unsigned)b << 16);
}

#define GLOAD16(gp, lp) __builtin_amdgcn_global_load_lds( \
    (const __attribute__((address_space(1))) void*)(gp), \
    (__attribute__((address_space(3))) void*)(lp), 16, 0, 0)
#define WAITVM(n) asm volatile("s_waitcnt vmcnt(" #n ")" ::: "memory")
#define LGKM0()   do { asm volatile("s_waitcnt lgkmcnt(0)" ::: "memory"); \
                       __builtin_amdgcn_sched_barrier(0); } while (0)
#define SBAR() __builtin_amdgcn_s_barrier()

// ================= conversion / prep =================
__global__ void k_conv_x(const float* __restrict__ in, short* __restrict__ out) {
  const int NG = RTOT * (DIN / 8);
  for (int g = blockIdx.x * 256 + threadIdx.x; g < NG; g += 2048 * 256) {
    int r = g >> 6, c8 = g & 63;
    int b = r >> 11, t = r & 2047;
    const float4* p = reinterpret_cast<const float4*>(in) + (size_t)g * 2;
    float4 f0 = p[0], f1 = p[1];
    short8 o;
    o[0]=f2bf(f0.x); o[1]=f2bf(f0.y); o[2]=f2bf(f0.z); o[3]=f2bf(f0.w);
    o[4]=f2bf(f1.x); o[5]=f2bf(f1.y); o[6]=f2bf(f1.z); o[7]=f2bf(f1.w);
    *reinterpret_cast<short8*>(out + ((size_t)(b * PSEQ + 16 + t) * DIN + c8 * 8)) = o;
  }
}

__global__ void k_zero_pad(short* __restrict__ Xp) {
  int idx = blockIdx.x * 256 + threadIdx.x;
  if (idx >= B_SZ * 16 * (DIN / 8)) return;
  int b = idx >> 10, rem = idx & 1023;
  int row16 = rem >> 6, c8 = rem & 63;
  const short8 z = {0,0,0,0,0,0,0,0};
  *reinterpret_cast<short8*>(Xp + ((size_t)(b * PSEQ + row16) * DIN + c8 * 8)) = z;
}

__global__ void k_transpose_bf16(const float* __restrict__ in, short* __restrict__ out,
                                 int rows, int cols) {
  __shared__ float t[32][33];
  int bx = blockIdx.x * 32, by = blockIdx.y * 32;
  int tx = threadIdx.x & 31, ty = threadIdx.x >> 5;
  #pragma unroll
  for (int j = 0; j < 32; j += 8)
    t[ty + j][tx] = in[(size_t)(by + ty + j) * cols + (bx + tx)];
  __syncthreads();
  #pragma unroll
  for (int j = 0; j < 32; j += 8)
    out[(size_t)(bx + ty + j) * rows + (by + tx)] = f2bf(t[tx][ty + j]);
}

__global__ void k_prep_M(const float* __restrict__ M, short* __restrict__ Mt) {
  int idx = blockIdx.x * 256 + threadIdx.x;
  if (idx >= DOUT * DIN) return;
  int o = idx / DIN, i = idx - o * DIN;
  const float* src = M + ((size_t)o * DIN + i) * KX;
  #pragma unroll
  for (int t = 0; t < KX; ++t)
    Mt[((size_t)t * DOUT + o) * DIN + i] = f2bf(src[t]);
}

// ================= chunked scan (uB is bf16) =================
__global__ void k_scan_E(const short* __restrict__ uB, const float* __restrict__ A,
                         float* __restrict__ E) {
  int blk = blockIdx.x, tid = threadIdx.x;
  int b = blk >> 5, c = blk & 31;
  int s0 = tid * 4;
  const short* base = uB + ((size_t)b * SEQ + (size_t)c * LC) * SDIM + s0;
  float a[4], h[4];
  #pragma unroll
  for (int j = 0; j < 4; ++j) { a[j] = A[s0 + j]; h[j] = 0.f; }
  for (int t = 0; t < LC; ++t) {
    bfx4 v = *reinterpret_cast<const bfx4*>(base + (size_t)t * SDIM);
    #pragma unroll
    for (int j = 0; j < 4; ++j) h[j] = fmaf(a[j], h[j], bf2f(v[j]));
  }
  float* ep = E + (size_t)blk * SDIM + s0;
  #pragma unroll
  for (int j = 0; j < 4; ++j) ep[j] = h[j];
}

__global__ void k_scan_S(const float* __restrict__ E, const float* __restrict__ A,
                         const float* __restrict__ h0, float* __restrict__ Sb) {
  int blk = blockIdx.x, tid = threadIdx.x;
  int b = blk >> 2;
  int s = ((blk & 3) << 8) + tid;
  float a = A[s], ap = a;
  #pragma unroll
  for (int q = 0; q < 6; ++q) ap *= ap;   // a^64
  float S = h0[s];
  for (int c = 0; c < NC; ++c) {
    size_t idx = ((size_t)b * NC + c) * SDIM + s;
    Sb[idx] = S;
    S = fmaf(ap, S, E[idx]);
  }
}

__global__ void k_scan_h(const short* __restrict__ uB, const float* __restrict__ A,
                         const float* __restrict__ Sb, short* __restrict__ hs) {
  int blk = blockIdx.x, tid = threadIdx.x;
  int b = blk >> 5, c = blk & 31;
  int s0 = tid * 4;
  const short* base = uB + ((size_t)b * SEQ + (size_t)c * LC) * SDIM + s0;
  short* hbase = hs + ((size_t)b * SEQ + (size_t)c * LC) * SDIM + s0;
  float a[4], h[4];
  #pragma unroll
  for (int j = 0; j < 4; ++j) {
    a[j] = A[s0 + j];
    h[j] = Sb[(size_t)blk * SDIM + s0 + j];
  }
  for (int t = 0; t < LC; ++t) {
    bfx4 v = *reinterpret_cast<const bfx4*>(base + (size_t)t * SDIM);
    bfx4 o;
    #pragma unroll
    for (int j = 0; j < 4; ++j) {
      h[j] = fmaf(a[j], h[j], bf2f(v[j]));
      o[j] = (unsigned short)f2bf(h[j]);
    }
    *reinterpret_cast<bfx4*>(hbase + (size_t)t * SDIM) = o;
  }
}

// ================= GEMM1: 128x128, 4 waves, dbuf + counted vmcnt (R5, proven) ==
__device__ __forceinline__ void stage128(const short* __restrict__ g, int ld,
                                         short* l, int tid) {
  int rsub = tid >> 3;
  int slot = (tid & 7) ^ (rsub & 7);
  #pragma unroll
  for (int i = 0; i < 4; ++i) {
    int row = i * 32 + rsub;
    GLOAD16(g + (size_t)row * ld + slot * 8, l + row * 64 + (tid & 7) * 8);
  }
}

__device__ __forceinline__ void mfma_tile(const short* lA, int aoff, const short* lB,
                                          int lane, int wm, int wn, f32x4 acc[4][4]) {
  int lr = lane & 15;
  int h  = lane >> 4;
  #pragma unroll
  for (int kk = 0; kk < 2; ++kk) {
    int kslot = kk * 4 + h;
    short8 af[4], bfr[4];
    #pragma unroll
    for (int mi = 0; mi < 4; ++mi) {
      int row = aoff + wm * 64 + mi * 16 + lr;
      af[mi] = *reinterpret_cast<const short8*>(lA + row * 64 + ((kslot ^ (row & 7)) << 3));
    }
    #pragma unroll
    for (int ni = 0; ni < 4; ++ni) {
      int row = wn * 64 + ni * 16 + lr;
      bfr[ni] = *reinterpret_cast<const short8*>(lB + row * 64 + ((kslot ^ (row & 7)) << 3));
    }
    __builtin_amdgcn_s_setprio(1);
    #pragma unroll
    for (int mi = 0; mi < 4; ++mi)
      #pragma unroll
      for (int ni = 0; ni < 4; ++ni)
        acc[mi][ni] = __builtin_amdgcn_mfma_f32_16x16x32_bf16(af[mi], bfr[ni], acc[mi][ni], 0, 0, 0);
    __builtin_amdgcn_s_setprio(0);
  }
}

__global__ __launch_bounds__(256) void k_gemm_uB(const short* __restrict__ Xp,
                                                 const short* __restrict__ Bt,
                                                 short* __restrict__ uB) {
  __shared__ __attribute__((aligned(16))) short lds[32768];
  short* A0 = lds;         short* B0 = lds + 8192;
  short* A1 = lds + 16384; short* B1 = lds + 24576;
  int tid = threadIdx.x, lane = tid & 63, w = tid >> 6, wm = w >> 1, wn = w & 1;
  long r0 = (long)blockIdx.x * 128;
  int  c0 = blockIdx.y * 128;
  int  b  = (int)(r0 >> 11);
  const short* Abase = Xp + (size_t)(r0 + 16 * (b + 1)) * DIN;
  const short* Bbase = Bt + (size_t)c0 * DIN;
  const f32x4 z4 = {0.f, 0.f, 0.f, 0.f};
  f32x4 acc[4][4];
  #pragma unroll
  for (int mi = 0; mi < 4; ++mi)
    #pragma unroll
    for (int ni = 0; ni < 4; ++ni) acc[mi][ni] = z4;

  stage128(Abase, DIN, A0, tid);      stage128(Bbase, DIN, B0, tid);
  stage128(Abase + 64, DIN, A1, tid); stage128(Bbase + 64, DIN, B1, tid);
  WAITVM(8);
  SBAR();
  for (int kt = 0; kt < 8; ++kt) {
    const short* a  = (kt & 1) ? A1 : A0;
    const short* bb = (kt & 1) ? B1 : B0;
    mfma_tile(a, 0, bb, lane, wm, wn, acc);
    SBAR();
    if (kt + 2 < 8) {
      short* ad = (kt & 1) ? A1 : A0;
      short* bd = (kt & 1) ? B1 : B0;
      stage128(Abase + (kt + 2) * 64, DIN, ad, tid);
      stage128(Bbase + (kt + 2) * 64, DIN, bd, tid);
      WAITVM(8);
    } else {
      WAITVM(0);
    }
    SBAR();
  }
  #pragma unroll
  for (int mi = 0; mi < 4; ++mi)
    #pragma unroll
    for (int ni = 0; ni < 4; ++ni)
      #pragma unroll
      for (int r = 0; r < 4; ++r) {
        long row = r0 + wm * 64 + mi * 16 + (lane >> 4) * 4 + r;
        int  col = c0 + wn * 64 + ni * 16 + (lane & 15);
        uB[(size_t)row * SDIM + col] = f2bf(acc[mi][ni][r]);
      }
}

// ================= GEMM2: 256x128 tile, 8 waves, stage-early + dbuf ==========
// LDS (shorts): A0[0,16384) B0[16384,24576) A1[24576,40960) B1[40960,49152)
// Phase2: Xs[0,17408) (A0+B0 region), M0 at 24576, M1 at 40960.

__device__ __forceinline__ void stageA256(const short* __restrict__ g, int ld,
                                          short* l, int tid) {
  int rsub = tid >> 3;
  int slot = (tid & 7) ^ (rsub & 7);
  #pragma unroll
  for (int i = 0; i < 4; ++i) {
    int row = i * 64 + rsub;
    GLOAD16(g + (size_t)row * ld + slot * 8, l + row * 64 + (tid & 7) * 8);
  }
}
__device__ __forceinline__ void stageB128(const short* __restrict__ g, int ld,
                                          short* l, int tid) {
  int rsub = tid >> 3;
  int slot = (tid & 7) ^ (rsub & 7);
  #pragma unroll
  for (int i = 0; i < 2; ++i) {
    int row = i * 64 + rsub;
    GLOAD16(g + (size_t)row * ld + slot * 8, l + row * 64 + (tid & 7) * 8);
  }
}
__device__ __forceinline__ void stageX272(const short* __restrict__ g, int ld,
                                          short* l, int tid) {
  stageA256(g, ld, l, tid);
  if (tid < 128) {
    int rsub = tid >> 3;
    int row = 256 + rsub;
    int slot = (tid & 7) ^ (row & 7);
    GLOAD16(g + (size_t)row * ld + slot * 8, l + row * 64 + (tid & 7) * 8);
  }
}

// one K=64 step: per wave 4x4 frags of 16x16, A rows wm*64.., B rows wn*64..
__device__ __forceinline__ void compute_step(const short* la, int aoff, const short* lb,
                                             int lane, int wm, int wn, f32x4 acc[4][4]) {
  int lr = lane & 15;
  int h  = lane >> 4;
  short8 af[4][2], bfr[4][2];
  #pragma unroll
  for (int kk = 0; kk < 2; ++kk) {
    int kslot = kk * 4 + h;
    #pragma unroll
    for (int mi = 0; mi < 4; ++mi) {
      int row = aoff + wm * 64 + mi * 16 + lr;
      af[mi][kk] = *reinterpret_cast<const short8*>(la + row * 64 + ((kslot ^ (row & 7)) << 3));
    }
    #pragma unroll
    for (int ni = 0; ni < 4; ++ni) {
      int row = wn * 64 + ni * 16 + lr;
      bfr[ni][kk] = *reinterpret_cast<const short8*>(lb + row * 64 + ((kslot ^ (row & 7)) << 3));
    }
  }
  __builtin_amdgcn_s_setprio(1);
  #pragma unroll
  for (int kk = 0; kk < 2; ++kk)
    #pragma unroll
    for (int mi = 0; mi < 4; ++mi)
      #pragma unroll
      for (int ni = 0; ni < 4; ++ni)
        acc[mi][ni] = __builtin_amdgcn_mfma_f32_16x16x32_bf16(af[mi][kk], bfr[ni][kk], acc[mi][ni], 0, 0, 0);
  __builtin_amdgcn_s_setprio(0);
}

__global__ __launch_bounds__(512) void k_gemm_out(const short* __restrict__ hs,
                                                  const short* __restrict__ Xp,
                                                  const short* __restrict__ Ct,
                                                  const short* __restrict__ Mt,
                                                  float* __restrict__ out) {
  __shared__ __attribute__((aligned(16))) short lds[49152];
  short* A0p = lds;          short* B0p = lds + 16384;
  short* A1p = lds + 24576;  short* B1p = lds + 40960;
  short* Xs  = lds;
  short* M0p = lds + 24576;  short* M1p = lds + 40960;
  int tid = threadIdx.x, lane = tid & 63, w = tid >> 6;
  int wm = w >> 1, wn = w & 1;                  // 4M x 2N waves, 64x64 each
  // XCD-bijective swizzle: XCD k gets 32 consecutive sw -> 32 row-blocks, one c0
  int bid = blockIdx.x;
  int sw  = (bid & 7) * 32 + (bid >> 3);        // 256 blocks, bijective
  long r0 = (long)(sw & 63) * 256;
  int  c0 = (sw >> 6) * 128;
  int  b  = (int)(r0 >> 11);
  const short* hsA = hs + (size_t)r0 * SDIM;
  const short* CtB = Ct + (size_t)c0 * SDIM;
  const short* Xa  = Xp + (size_t)(r0 + 16 * (b + 1) - 16) * DIN;
  const short* MtB = Mt + (size_t)c0 * DIN;

  const f32x4 z4 = {0.f, 0.f, 0.f, 0.f};
  f32x4 acc[4][4];
  #pragma unroll
  for (int mi = 0; mi < 4; ++mi)
    #pragma unroll
    for (int ni = 0; ni < 4; ++ni) acc[mi][ni] = z4;

  // ---- phase 1: hs @ Ct^T, K = 1024 (16 steps) ----
  stageA256(hsA, SDIM, A0p, tid);
  stageB128(CtB, SDIM, B0p, tid);
  WAITVM(0);
  SBAR();
  for (int s = 0; s < 16; ++s) {
    const short* la = (s & 1) ? A1p : A0p;
    const short* lb = (s & 1) ? B1p : B0p;
    short* na = (s & 1) ? A0p : A1p;
    short* nb = (s & 1) ? B0p : B1p;
    // issue next step's stages FIRST (hidden under this step's MFMAs)
    if (s + 1 < 16) {
      stageA256(hsA + (s + 1) * 64, SDIM, na, tid);
      stageB128(CtB + (s + 1) * 64, SDIM, nb, tid);
    } else {
      stageX272(Xa, DIN, Xs, tid);      // prefetch conv X into A0/B0 (s=15: free)
    }
    compute_step(la, 0, lb, lane, wm, wn, acc);
    LGKM0();           // all LDS reads of this step done before refill can land
    WAITVM(0);
    SBAR();
  }

  // ---- phase 2: AR conv, Xs reused across 10 taps per k0-slice ----
  stageB128(MtB, DIN, M0p, tid);      // tap 0, slice 0
  WAITVM(0);
  SBAR();
  for (int k0 = 0; k0 < 8; ++k0) {
    int kc = k0 * 64;
    for (int tap = 0; tap < KX; ++tap) {
      const short* lm = (tap & 1) ? M1p : M0p;
      short* nm = (tap & 1) ? M0p : M1p;
      if (tap + 1 < KX)
        stageB128(MtB + (size_t)(tap + 1) * DOUT * DIN + kc, DIN, nm, tid);
      else if (k0 + 1 < 8)
        stageB128(MtB + kc + 64, DIN, M0p, tid);   // next slice, tap 0
      compute_step(Xs, 16 - tap, lm, lane, wm, wn, acc);
      LGKM0();
      WAITVM(0);
      SBAR();
    }
    if (k0 + 1 < 8) {
      stageX272(Xa + kc + 64, DIN, Xs, tid);
      WAITVM(0);
      SBAR();
    }
  }

  #pragma unroll
  for (int mi = 0; mi < 4; ++mi)
    #pragma unroll
    for (int ni = 0; ni < 4; ++ni)
      #pragma unroll
      for (int r = 0; r < 4; ++r) {
        long row = r0 + wm * 64 + mi * 16 + (lane >> 4) * 4 + r;
        int  col = c0 + wn * 64 + ni * 16 + (lane & 15);
        out[(size_t)row * DOUT + col] = acc[mi][ni][r];
      }
}

// ================= launch =================
extern "C" void kernel_launch(void* const* d_in, const int* in_sizes, int n_in,
                              void* d_out, int out_size, void* d_ws, size_t ws_size,
                              hipStream_t stream) {
  (void)in_sizes; (void)n_in; (void)out_size; (void)ws_size;
  const float* x  = (const float*)d_in[0];
  const float* h0 = (const float*)d_in[1];
  const float* A  = (const float*)d_in[2];
  const float* B  = (const float*)d_in[3];
  const float* C  = (const float*)d_in[4];
  const float* M  = (const float*)d_in[5];
  float* out = (float*)d_out;
  char* ws = (char*)d_ws;

  short* Xp  = (short*)(ws + OFF_XP);
  short* uB  = (short*)(ws + OFF_UB);
  short* hsb = (short*)(ws + OFF_HS);
  short* Bt  = (short*)(ws + OFF_BT);
  short* Ct  = (short*)(ws + OFF_CT);
  short* Mt  = (short*)(ws + OFF_MT);
  // scan scratch inside d_out (fully overwritten by k_gemm_out afterwards)
  float* E   = out;                    // B_SZ*NC*SDIM f32 = 1 MiB
  float* Sb  = out + B_SZ * NC * SDIM; // 1 MiB

  k_conv_x<<<2048, 256, 0, stream>>>(x, Xp);
  k_zero_pad<<<32, 256, 0, stream>>>(Xp);
  k_transpose_bf16<<<dim3(SDIM / 32, DIN / 32), 256, 0, stream>>>(B, Bt, DIN, SDIM);
  k_transpose_bf16<<<dim3(DOUT / 32, SDIM / 32), 256, 0, stream>>>(C, Ct, SDIM, DOUT);
  k_prep_M<<<(DOUT * DIN + 255) / 256, 256, 0, stream>>>(M, Mt);

  k_gemm_uB<<<dim3(RTOT / 128, SDIM / 128), 256, 0, stream>>>(Xp, Bt, uB);

  k_scan_E<<<B_SZ * NC, 256, 0, stream>>>(uB, A, E);
  k_scan_S<<<B_SZ * 4, 256, 0, stream>>>(E, A, h0, Sb);
  k_scan_h<<<B_SZ * NC, 256, 0, stream>>>(uB, A, Sb, hsb);

  k_gemm_out<<<256, 512, 0, stream>>>(hsb, Xp, Ct, Mt, out);
}